// Round 2
// baseline (514.664 us; speedup 1.0000x reference)
//
#include <hip/hip_runtime.h>
#include <hip/hip_bf16.h>

#define B_ 32
#define N_ 1024
#define M_ 256
#define D_ 512

typedef __attribute__((ext_vector_type(8))) short short8;
typedef __attribute__((ext_vector_type(4))) float f32x4;

// ---- workspace layout (float offsets) ----
#define OFF_S     ((size_t)0)          // fp32 S, B*N*M
#define OFF_CTXW  ((size_t)8388608)    // bf16 ctx*w_m [B][N][D]  (dead after s_gemm)
#define OFF_ANM   ((size_t)8388608)    // bf16 A [B][N][M]  (overlays ctxw)
#define OFF_BMT   ((size_t)12582912)   // bf16 Bm^T [B][M][N] (overlays ctxw 2nd half)
#define OFF_QB    ((size_t)16777216)   // bf16 qry [B][M][D]; Q2CT overlays after s_gemm
#define OFF_QT    ((size_t)18874368)   // bf16 qry^T [B][D][M]
#define OFF_CT    ((size_t)20971520)   // bf16 ctx^T [B][D][N]
#define OFF_CDOT  ((size_t)29360128)
#define OFF_QDOT  ((size_t)29392896)
#define OFF_RMAX  ((size_t)29401088)
#define OFF_RSUM  ((size_t)29433856)
#define OFF_CMAX  ((size_t)29466624)
#define OFF_CSUM  ((size_t)29474816)
#define OFF_PMAX  ((size_t)29483008)
#define OFF_PSUM  ((size_t)29614080)
#define OFF_RPMAX ((size_t)29745152)   // fp32 row partials [B*N][4]
#define OFF_RPSUM ((size_t)29876224)   // fp32 row partials [B*N][4]

// ---------------- fused prep: cast*w_m / transpose / dot ----------------
// One kernel covers both ctx (y < N/64) and qry (y >= N/64) tiles.
// Reads input once; writes row-major bf16 (ctx*w_m or qry), transposed bf16,
// and atomically accumulates dot products with w_c / w_q.
__global__ __launch_bounds__(256) void prep_all(
    const float* __restrict__ ctx, const float* __restrict__ qry,
    const float* __restrict__ w,
    __hip_bfloat16* __restrict__ ctxw, __hip_bfloat16* __restrict__ cT,
    float* __restrict__ cdot,
    __hip_bfloat16* __restrict__ qb, __hip_bfloat16* __restrict__ qT,
    float* __restrict__ qdot)
{
    __shared__ float t[64][65];
    int b = blockIdx.z, d0 = blockIdx.x * 64;
    int tr = threadIdx.x >> 6, tc = threadIdx.x & 63;
    const float* src;
    __hip_bfloat16* rowdst;
    __hip_bfloat16* trdst;
    float* dotdst;
    float wrow, wdot;
    int ldt;
    if (blockIdx.y < N_ / 64) {
        int r0 = blockIdx.y * 64;
        src    = ctx + ((size_t)b * N_ + r0) * D_ + d0;
        rowdst = ctxw + ((size_t)b * N_ + r0) * D_ + d0;
        trdst  = cT + ((size_t)b * D_ + d0) * N_ + r0;
        dotdst = cdot + b * N_ + r0;
        wrow = w[2 * D_ + d0 + tc];   // w_m
        wdot = w[D_ + d0 + tc];       // w_c
        ldt = N_;
    } else {
        int r0 = (blockIdx.y - N_ / 64) * 64;
        src    = qry + ((size_t)b * M_ + r0) * D_ + d0;
        rowdst = qb + ((size_t)b * M_ + r0) * D_ + d0;
        trdst  = qT + ((size_t)b * D_ + d0) * M_ + r0;
        dotdst = qdot + b * M_ + r0;
        wrow = 1.0f;
        wdot = w[d0 + tc];            // w_q
        ldt = M_;
    }
#pragma unroll
    for (int i = 0; i < 16; ++i) {
        int r = tr + i * 4;
        float x = src[(size_t)r * D_ + tc];
        t[r][tc] = x;
        rowdst[(size_t)r * D_ + tc] = __float2bfloat16(x * wrow);
        float p = x * wdot;
#pragma unroll
        for (int off = 32; off; off >>= 1) p += __shfl_down(p, off, 64);
        if (tc == 0) atomicAdd(dotdst + r, p);
    }
    __syncthreads();
#pragma unroll
    for (int i = 0; i < 16; ++i)
        trdst[(size_t)(tr + i * 4) * ldt + tc] = __float2bfloat16(t[tc][tr + i * 4]);
}

// ---------------- MFMA 128x128 tile core (2-phase double-buffered) ----------------

__device__ __forceinline__ void gl2lds16(const __hip_bfloat16* g, __hip_bfloat16* l) {
    __builtin_amdgcn_global_load_lds(
        (const __attribute__((address_space(1))) unsigned int*)g,
        (__attribute__((address_space(3))) unsigned int*)l, 16, 0, 0);
}

// A: [128 rows][K] row-major bf16, B: [128 cols][K] row-major bf16.
// acc[fi][fj] += A_tile * B_tile^T over K.
// As, Bs: double-buffered, 2*4096 elements each.
// Schedule per K-step: issue next-tile global_load_lds FIRST, then ds_read+MFMA
// current tile, then one barrier (its implicit vmcnt drain lands after compute).
template<int KTOT>
__device__ __forceinline__ void mfma128(
    const __hip_bfloat16* __restrict__ Abase, int lda,
    const __hip_bfloat16* __restrict__ Bbase, int ldb,
    __hip_bfloat16* As, __hip_bfloat16* Bs, f32x4 acc[4][4])
{
    const int tid = threadIdx.x;
    const int w = tid >> 6, lane = tid & 63;
    const int quad = lane >> 4, lr = lane & 15;
    const int wr = w >> 1, wc = w & 1;
    const int srow = w * 32 + (lane >> 2);
    const int scol = (lane & 3) * 8;
    const __hip_bfloat16* ga0 = Abase + (size_t)srow * lda + scol;
    const __hip_bfloat16* ga1 = ga0 + (size_t)16 * lda;
    const __hip_bfloat16* gb0 = Bbase + (size_t)srow * ldb + scol;
    const __hip_bfloat16* gb1 = gb0 + (size_t)16 * ldb;
    const int lws = w * 1024;
    const int aoff = (wr * 64 + lr) * 32 + quad * 8;
    const int boff = (wc * 64 + lr) * 32 + quad * 8;

    // prologue: stage k=0 into buffer 0
    gl2lds16(ga0, As + lws); gl2lds16(ga1, As + lws + 512);
    gl2lds16(gb0, Bs + lws); gl2lds16(gb1, Bs + lws + 512);
    __syncthreads();   // compiler emits vmcnt(0) drain before s_barrier

    int cur = 0;
    for (int k0 = 0; k0 < KTOT; k0 += 32) {
        const bool more = (k0 + 32 < KTOT);
        if (more) {
            const int nb = (cur ^ 1) << 12;
            gl2lds16(ga0 + 32, As + nb + lws); gl2lds16(ga1 + 32, As + nb + lws + 512);
            gl2lds16(gb0 + 32, Bs + nb + lws); gl2lds16(gb1 + 32, Bs + nb + lws + 512);
            ga0 += 32; ga1 += 32; gb0 += 32; gb1 += 32;
        }
        const int cb = cur << 12;
        short8 a[4], bb[4];
        const short8* ap = (const short8*)(As + cb + aoff);
        const short8* bp = (const short8*)(Bs + cb + boff);
#pragma unroll
        for (int fi = 0; fi < 4; ++fi) a[fi] = ap[fi * 64];
#pragma unroll
        for (int fj = 0; fj < 4; ++fj) bb[fj] = bp[fj * 64];
#pragma unroll
        for (int fi = 0; fi < 4; ++fi)
#pragma unroll
            for (int fj = 0; fj < 4; ++fj)
                acc[fi][fj] = __builtin_amdgcn_mfma_f32_16x16x32_bf16(
                    a[fi], bb[fj], acc[fi][fj], 0, 0, 0);
        if (more) { __syncthreads(); cur ^= 1; }
    }
}

// dual-B variant: shared A tile, two accumulators.
template<int KTOT>
__device__ __forceinline__ void mfma128x2(
    const __hip_bfloat16* __restrict__ Abase, int lda,
    const __hip_bfloat16* __restrict__ B1base,
    const __hip_bfloat16* __restrict__ B2base, int ldb,
    __hip_bfloat16* As, __hip_bfloat16* B1s, __hip_bfloat16* B2s,
    f32x4 acc1[4][4], f32x4 acc2[4][4])
{
    const int tid = threadIdx.x;
    const int w = tid >> 6, lane = tid & 63;
    const int quad = lane >> 4, lr = lane & 15;
    const int wr = w >> 1, wc = w & 1;
    const int srow = w * 32 + (lane >> 2);
    const int scol = (lane & 3) * 8;
    const __hip_bfloat16* ga0 = Abase + (size_t)srow * lda + scol;
    const __hip_bfloat16* ga1 = ga0 + (size_t)16 * lda;
    const __hip_bfloat16* gb10 = B1base + (size_t)srow * ldb + scol;
    const __hip_bfloat16* gb11 = gb10 + (size_t)16 * ldb;
    const __hip_bfloat16* gb20 = B2base + (size_t)srow * ldb + scol;
    const __hip_bfloat16* gb21 = gb20 + (size_t)16 * ldb;
    const int lws = w * 1024;
    const int aoff = (wr * 64 + lr) * 32 + quad * 8;
    const int boff = (wc * 64 + lr) * 32 + quad * 8;

    gl2lds16(ga0, As + lws);  gl2lds16(ga1, As + lws + 512);
    gl2lds16(gb10, B1s + lws); gl2lds16(gb11, B1s + lws + 512);
    gl2lds16(gb20, B2s + lws); gl2lds16(gb21, B2s + lws + 512);
    __syncthreads();

    int cur = 0;
    for (int k0 = 0; k0 < KTOT; k0 += 32) {
        const bool more = (k0 + 32 < KTOT);
        if (more) {
            const int nb = (cur ^ 1) << 12;
            gl2lds16(ga0 + 32, As + nb + lws);   gl2lds16(ga1 + 32, As + nb + lws + 512);
            gl2lds16(gb10 + 32, B1s + nb + lws); gl2lds16(gb11 + 32, B1s + nb + lws + 512);
            gl2lds16(gb20 + 32, B2s + nb + lws); gl2lds16(gb21 + 32, B2s + nb + lws + 512);
            ga0 += 32; ga1 += 32; gb10 += 32; gb11 += 32; gb20 += 32; gb21 += 32;
        }
        const int cb = cur << 12;
        short8 a[4], b1[4], b2[4];
        const short8* ap = (const short8*)(As + cb + aoff);
        const short8* bp1 = (const short8*)(B1s + cb + boff);
        const short8* bp2 = (const short8*)(B2s + cb + boff);
#pragma unroll
        for (int fi = 0; fi < 4; ++fi) a[fi] = ap[fi * 64];
#pragma unroll
        for (int fj = 0; fj < 4; ++fj) { b1[fj] = bp1[fj * 64]; b2[fj] = bp2[fj * 64]; }
#pragma unroll
        for (int fi = 0; fi < 4; ++fi)
#pragma unroll
            for (int fj = 0; fj < 4; ++fj) {
                acc1[fi][fj] = __builtin_amdgcn_mfma_f32_16x16x32_bf16(
                    a[fi], b1[fj], acc1[fi][fj], 0, 0, 0);
                acc2[fi][fj] = __builtin_amdgcn_mfma_f32_16x16x32_bf16(
                    a[fi], b2[fj], acc2[fi][fj], 0, 0, 0);
            }
        if (more) { __syncthreads(); cur ^= 1; }
    }
}

#define ACC_INIT(acc) \
    _Pragma("unroll") for (int i_ = 0; i_ < 4; ++i_) \
    _Pragma("unroll") for (int j_ = 0; j_ < 4; ++j_) acc[i_][j_] = (f32x4){0.f, 0.f, 0.f, 0.f};

#define EPI_IDX const int tid = threadIdx.x, lane = tid & 63, quad = lane >> 4, lr = lane & 15; \
    const int wr = tid >> 7, wc = (tid >> 6) & 1;

// S[n][m] = ctxw[n][:] . qry[m][:] + cdot[n] + qdot[m]
// Epilogue additionally emits softmax partials:
//   row partials (over 64-col slabs, 4 per row) -> rpmax/rpsum
//   col partials (over 64-row slabs, 16 per col) -> pmax/psum
__global__ __launch_bounds__(256) void s_gemm_stats(
    const __hip_bfloat16* __restrict__ ctxw, const __hip_bfloat16* __restrict__ qryb,
    const float* __restrict__ cdot, const float* __restrict__ qdot,
    const int* __restrict__ q_mask, const int* __restrict__ c_mask,
    float* __restrict__ S,
    float* __restrict__ rpmax, float* __restrict__ rpsum,
    float* __restrict__ pmax, float* __restrict__ psum)
{
    __shared__ __align__(16) __hip_bfloat16 As[8192], Bs[8192];
    const int b = blockIdx.z, n0 = blockIdx.y * 128, m0 = blockIdx.x * 128;
    f32x4 acc[4][4];
    ACC_INIT(acc)
    mfma128<512>(ctxw + ((size_t)b * N_ + n0) * D_, D_,
                 qryb + ((size_t)b * M_ + m0) * D_, D_, As, Bs, acc);
    EPI_IDX
    // per-lane row metadata: n(fi,r) = n0 + wr*64 + fi*16 + quad*4 + r
    float cd[4][4]; int cmv[4][4];
#pragma unroll
    for (int fi = 0; fi < 4; ++fi)
#pragma unroll
        for (int r = 0; r < 4; ++r) {
            int n = n0 + wr * 64 + fi * 16 + quad * 4 + r;
            cd[fi][r] = cdot[b * N_ + n];
            cmv[fi][r] = c_mask[b * N_ + n];
        }
    // per-lane col metadata: m(fj) = m0 + wc*64 + fj*16 + lr
    float qd[4]; int qmv[4];
#pragma unroll
    for (int fj = 0; fj < 4; ++fj) {
        int m = m0 + wc * 64 + fj * 16 + lr;
        qd[fj] = qdot[b * M_ + m];
        qmv[fj] = q_mask[b * M_ + m];
    }
    // store S
#pragma unroll
    for (int fi = 0; fi < 4; ++fi)
#pragma unroll
        for (int r = 0; r < 4; ++r) {
            int n = n0 + wr * 64 + fi * 16 + quad * 4 + r;
            size_t rowoff = ((size_t)b * N_ + n) * M_;
#pragma unroll
            for (int fj = 0; fj < 4; ++fj) {
                int m = m0 + wc * 64 + fj * 16 + lr;
                S[rowoff + m] = acc[fi][fj][r] + cd[fi][r] + qd[fj];
            }
        }
    // ---- row partial stats (reduce over 64 cols held by 16 lanes x 4 fj) ----
    const int part = blockIdx.x * 2 + wc;   // which 64-col slab (0..3)
#pragma unroll
    for (int fi = 0; fi < 4; ++fi)
#pragma unroll
        for (int r = 0; r < 4; ++r) {
            float xs[4], mx = -1e30f;
#pragma unroll
            for (int fj = 0; fj < 4; ++fj) {
                xs[fj] = qmv[fj] ? (acc[fi][fj][r] + cd[fi][r] + qd[fj]) : -1e9f;
                mx = fmaxf(mx, xs[fj]);
            }
#pragma unroll
            for (int off = 1; off < 16; off <<= 1)
                mx = fmaxf(mx, __shfl_xor(mx, off, 64));
            float se = 0.f;
#pragma unroll
            for (int fj = 0; fj < 4; ++fj) se += __expf(xs[fj] - mx);
#pragma unroll
            for (int off = 1; off < 16; off <<= 1)
                se += __shfl_xor(se, off, 64);
            if (lr == 0) {
                int n = n0 + wr * 64 + fi * 16 + quad * 4 + r;
                rpmax[((size_t)b * N_ + n) * 4 + part] = mx;
                rpsum[((size_t)b * N_ + n) * 4 + part] = se;
            }
        }
    // ---- col partial stats (reduce over 64 rows: 16 in-lane x 4 quads) ----
    const int ch = blockIdx.y * 2 + wr;     // which 64-row slab (0..15)
#pragma unroll
    for (int fj = 0; fj < 4; ++fj) {
        float mx = -1e30f;
#pragma unroll
        for (int fi = 0; fi < 4; ++fi)
#pragma unroll
            for (int r = 0; r < 4; ++r) {
                float x = cmv[fi][r] ? (acc[fi][fj][r] + cd[fi][r] + qd[fj]) : -1e9f;
                mx = fmaxf(mx, x);
            }
        mx = fmaxf(mx, __shfl_xor(mx, 16, 64));
        mx = fmaxf(mx, __shfl_xor(mx, 32, 64));
        float se = 0.f;
#pragma unroll
        for (int fi = 0; fi < 4; ++fi)
#pragma unroll
            for (int r = 0; r < 4; ++r) {
                float x = cmv[fi][r] ? (acc[fi][fj][r] + cd[fi][r] + qd[fj]) : -1e9f;
                se += __expf(x - mx);
            }
        se += __shfl_xor(se, 16, 64);
        se += __shfl_xor(se, 32, 64);
        if (lane < 16) {
            int m = m0 + wc * 64 + fj * 16 + lr;
            pmax[((size_t)b * 16 + ch) * M_ + m] = mx;
            psum[((size_t)b * 16 + ch) * M_ + m] = se;
        }
    }
}

// Q2CT[d][m] = sum_n ctxT[d][n] * BmT[m][n]
__global__ __launch_bounds__(256) void q2cpart_mfma(
    const __hip_bfloat16* __restrict__ ctxT, const __hip_bfloat16* __restrict__ BmT,
    __hip_bfloat16* __restrict__ Q2CT)
{
    __shared__ __align__(16) __hip_bfloat16 As[8192], Bs[8192];
    const int b = blockIdx.z, d0 = blockIdx.y * 128, m0 = blockIdx.x * 128;
    f32x4 acc[4][4];
    ACC_INIT(acc)
    mfma128<1024>(ctxT + ((size_t)b * D_ + d0) * N_, N_,
                  BmT + ((size_t)b * M_ + m0) * N_, N_, As, Bs, acc);
    EPI_IDX
#pragma unroll
    for (int fi = 0; fi < 4; ++fi) {
#pragma unroll
        for (int r = 0; r < 4; ++r) {
            int d = d0 + wr * 64 + fi * 16 + quad * 4 + r;
#pragma unroll
            for (int fj = 0; fj < 4; ++fj) {
                int m = m0 + wc * 64 + fj * 16 + lr;
                Q2CT[((size_t)b * D_ + d) * M_ + m] = __float2bfloat16(acc[fi][fj][r]);
            }
        }
    }
}

// fused: c2q[n][d] = sum_m A[n][m] qryT[d][m]
//        q2c[n][d] = sum_m A[n][m] Q2CT[d][m]
// writes all 4 output chunks: [ctx, c2q, ctx*c2q, ctx*q2c]
__global__ __launch_bounds__(256) void out_fused_mfma(
    const __hip_bfloat16* __restrict__ Anm, const __hip_bfloat16* __restrict__ qryT,
    const __hip_bfloat16* __restrict__ Q2CT, const float* __restrict__ ctx,
    float* __restrict__ out)
{
    __shared__ __align__(16) __hip_bfloat16 As[8192], B1s[8192], B2s[8192];
    const int b = blockIdx.z, n0 = blockIdx.y * 128, d0 = blockIdx.x * 128;
    f32x4 acc1[4][4], acc2[4][4];
    ACC_INIT(acc1)
    ACC_INIT(acc2)
    mfma128x2<256>(Anm + ((size_t)b * N_ + n0) * M_, M_,
                   qryT + ((size_t)b * D_ + d0) * M_,
                   Q2CT + ((size_t)b * D_ + d0) * M_, M_,
                   As, B1s, B2s, acc1, acc2);
    EPI_IDX
#pragma unroll
    for (int fi = 0; fi < 4; ++fi) {
#pragma unroll
        for (int r = 0; r < 4; ++r) {
            int n = n0 + wr * 64 + fi * 16 + quad * 4 + r;
            size_t ibase = ((size_t)b * N_ + n) * D_;
            size_t obase = ((size_t)b * N_ + n) * (4 * D_);
#pragma unroll
            for (int fj = 0; fj < 4; ++fj) {
                int d = d0 + wc * 64 + fj * 16 + lr;
                float c = ctx[ibase + d];
                float v1 = acc1[fi][fj][r];
                float v2 = acc2[fi][fj][r];
                out[obase + d] = c;
                out[obase + D_ + d] = v1;
                out[obase + 2 * D_ + d] = c * v1;
                out[obase + 3 * D_ + d] = c * v2;
            }
        }
    }
}

// ---------------- stats combine (row + col in one launch) ----------------

__global__ __launch_bounds__(256) void combine_stats(
    const float* __restrict__ pmax, const float* __restrict__ psum,
    const float* __restrict__ rpmax, const float* __restrict__ rpsum,
    float* __restrict__ cmax, float* __restrict__ csum,
    float* __restrict__ rmax, float* __restrict__ rsum)
{
    int idx = blockIdx.x * 256 + threadIdx.x;
    if (idx < B_ * M_) {
        int b = idx >> 8, m = idx & 255;
        float mx = -1e30f;
#pragma unroll
        for (int ch = 0; ch < 16; ++ch)
            mx = fmaxf(mx, pmax[((size_t)b * 16 + ch) * M_ + m]);
        float sm = 0.f;
#pragma unroll
        for (int ch = 0; ch < 16; ++ch)
            sm += psum[((size_t)b * 16 + ch) * M_ + m] *
                  __expf(pmax[((size_t)b * 16 + ch) * M_ + m] - mx);
        cmax[idx] = mx; csum[idx] = sm;
    } else {
        int row = idx - B_ * M_;
        float mx = -1e30f;
#pragma unroll
        for (int p = 0; p < 4; ++p)
            mx = fmaxf(mx, rpmax[(size_t)row * 4 + p]);
        float sm = 0.f;
#pragma unroll
        for (int p = 0; p < 4; ++p)
            sm += rpsum[(size_t)row * 4 + p] *
                  __expf(rpmax[(size_t)row * 4 + p] - mx);
        rmax[row] = mx; rsum[row] = sm;
    }
}

// A -> Anm (bf16, [n][m]); Bm -> BmT (bf16, [m][n] via LDS transpose)
__global__ __launch_bounds__(256) void normalize_kernel(
    const float* __restrict__ S, __hip_bfloat16* __restrict__ Anm,
    __hip_bfloat16* __restrict__ BmT,
    const int* __restrict__ q_mask, const int* __restrict__ c_mask,
    const float* __restrict__ rmax, const float* __restrict__ rsum,
    const float* __restrict__ cmax, const float* __restrict__ csum)
{
    __shared__ float t[64][65];
    int b = blockIdx.z, n0 = blockIdx.y * 64, m0 = blockIdx.x * 64;
    int tr = threadIdx.x >> 6, tc = threadIdx.x & 63;
    int m = m0 + tc;
    int qm = q_mask[b * M_ + m];
    float cmx = cmax[b * M_ + m], csm = csum[b * M_ + m];
#pragma unroll
    for (int i = 0; i < 16; ++i) {
        int n = n0 + tr + i * 4;
        size_t idx = ((size_t)b * N_ + n) * M_ + m;
        float s = S[idx];
        float a  = qm ? __expf(s - rmax[b * N_ + n]) / rsum[b * N_ + n] : 0.f;
        float bm = c_mask[b * N_ + n] ? __expf(s - cmx) / csm : 0.f;
        Anm[idx] = __float2bfloat16(a);
        t[tc][tr + i * 4] = bm;
    }
    __syncthreads();
#pragma unroll
    for (int i = 0; i < 16; ++i) {
        int ml = tr + i * 4;
        BmT[((size_t)b * M_ + m0 + ml) * N_ + n0 + tc] = __float2bfloat16(t[ml][tc]);
    }
}

extern "C" void kernel_launch(void* const* d_in, const int* in_sizes, int n_in,
                              void* d_out, int out_size, void* d_ws, size_t ws_size,
                              hipStream_t stream) {
    const float* ctx   = (const float*)d_in[0];
    const float* qry   = (const float*)d_in[1];
    const int*   cmask = (const int*)d_in[2];
    const int*   qmask = (const int*)d_in[3];
    const float* w     = (const float*)d_in[4];
    float* out = (float*)d_out;
    float* ws  = (float*)d_ws;

    float* S = ws + OFF_S;
    __hip_bfloat16* ctxw = (__hip_bfloat16*)(ws + OFF_CTXW);
    __hip_bfloat16* Anm  = (__hip_bfloat16*)(ws + OFF_ANM);
    __hip_bfloat16* BmT  = (__hip_bfloat16*)(ws + OFF_BMT);
    __hip_bfloat16* qb   = (__hip_bfloat16*)(ws + OFF_QB);
    __hip_bfloat16* Q2CT = (__hip_bfloat16*)(ws + OFF_QB);
    __hip_bfloat16* qT   = (__hip_bfloat16*)(ws + OFF_QT);
    __hip_bfloat16* cT   = (__hip_bfloat16*)(ws + OFF_CT);
    float* cdot = ws + OFF_CDOT;
    float* qdot = ws + OFF_QDOT;
    float* rmax = ws + OFF_RMAX;
    float* rsum = ws + OFF_RSUM;
    float* cmx  = ws + OFF_CMAX;
    float* csm  = ws + OFF_CSUM;
    float* pmax = ws + OFF_PMAX;
    float* psum = ws + OFF_PSUM;
    float* rpmax = ws + OFF_RPMAX;
    float* rpsum = ws + OFF_RPSUM;

    // zero dot accumulators (cdot and qdot are contiguous)
    hipMemsetAsync(cdot, 0, (size_t)(B_ * N_ + B_ * M_) * sizeof(float), stream);

    dim3 gp(D_ / 64, (N_ + M_) / 64, B_);
    prep_all<<<gp, 256, 0, stream>>>(ctx, qry, w, ctxw, cT, cdot, qb, qT, qdot);

    dim3 gS(M_ / 128, N_ / 128, B_);
    s_gemm_stats<<<gS, 256, 0, stream>>>(ctxw, qb, cdot, qdot, qmask, cmask,
                                         S, rpmax, rpsum, pmax, psum);

    combine_stats<<<(B_ * M_ + B_ * N_) / 256, 256, 0, stream>>>(
        pmax, psum, rpmax, rpsum, cmx, csm, rmax, rsum);

    dim3 gN(M_ / 64, N_ / 64, B_);
    normalize_kernel<<<gN, 256, 0, stream>>>(S, Anm, BmT, qmask, cmask,
                                             rmax, rsum, cmx, csm);

    dim3 gP(M_ / 128, D_ / 128, B_);
    q2cpart_mfma<<<gP, 256, 0, stream>>>(cT, BmT, Q2CT);

    dim3 gO(D_ / 128, N_ / 128, B_);
    out_fused_mfma<<<gO, 256, 0, stream>>>(Anm, qT, Q2CT, ctx, out);
}

// Round 3
// 481.993 us; speedup vs baseline: 1.0678x; 1.0678x over previous
//
#include <hip/hip_runtime.h>
#include <hip/hip_bf16.h>

#define B_ 32
#define N_ 1024
#define M_ 256
#define D_ 512

typedef __attribute__((ext_vector_type(8))) short short8;
typedef __attribute__((ext_vector_type(4))) float f32x4;

// ---- workspace layout (float offsets) ----
#define OFF_S     ((size_t)0)          // fp32 S, B*N*M
#define OFF_CTXW  ((size_t)8388608)    // bf16 ctx*w_m [B][N][D]  (dead after s_gemm)
#define OFF_ANM   ((size_t)8388608)    // bf16 A [B][N][M]  (overlays ctxw)
#define OFF_BMT   ((size_t)12582912)   // bf16 Bm^T [B][M][N] (overlays ctxw 2nd half)
#define OFF_QB    ((size_t)16777216)   // bf16 qry [B][M][D]; Q2CT overlays after s_gemm
#define OFF_QT    ((size_t)18874368)   // bf16 qry^T [B][D][M]
#define OFF_CT    ((size_t)20971520)   // bf16 ctx^T [B][D][N]
#define OFF_CDOT  ((size_t)29360128)
#define OFF_QDOT  ((size_t)29392896)
#define OFF_PMAX  ((size_t)29483008)
#define OFF_PSUM  ((size_t)29614080)
#define OFF_RPMAX ((size_t)29745152)   // fp32 row partials [B*N][4]
#define OFF_RPSUM ((size_t)29876224)   // fp32 row partials [B*N][4]

// ---------------- fused prep: cast*w_m / transpose / dot ----------------
// One kernel covers both ctx (y < N/64) and qry (y >= N/64) 64x64 tiles.
// Vectorized: float4 loads, ushort4 row-major bf16 stores, short8 transposed
// stores via LDS staging. Dot products reduced per 16-lane segment + atomicAdd.
__global__ __launch_bounds__(256) void prep_all(
    const float* __restrict__ ctx, const float* __restrict__ qry,
    const float* __restrict__ w,
    __hip_bfloat16* __restrict__ ctxw, __hip_bfloat16* __restrict__ cT,
    float* __restrict__ cdot,
    __hip_bfloat16* __restrict__ qb, __hip_bfloat16* __restrict__ qT,
    float* __restrict__ qdot)
{
    __shared__ float t[64][65];
    const int b = blockIdx.z, d0 = blockIdx.x * 64;
    const int tid = threadIdx.x;
    const float* src;
    __hip_bfloat16* rowdst;
    __hip_bfloat16* trdst;
    float* dotdst;
    int ldt;
    float4 wmv, wdv;
    const int lr16 = tid & 15, rband = tid >> 4;
    const int c = lr16 * 4;
    if (blockIdx.y < N_ / 64) {
        int r0 = blockIdx.y * 64;
        src    = ctx + ((size_t)b * N_ + r0) * D_ + d0;
        rowdst = ctxw + ((size_t)b * N_ + r0) * D_ + d0;
        trdst  = cT + ((size_t)b * D_ + d0) * N_ + r0;
        dotdst = cdot + b * N_ + r0;
        wmv = *(const float4*)(w + 2 * D_ + d0 + c);   // w_m
        wdv = *(const float4*)(w + D_ + d0 + c);       // w_c
        ldt = N_;
    } else {
        int r0 = (blockIdx.y - N_ / 64) * 64;
        src    = qry + ((size_t)b * M_ + r0) * D_ + d0;
        rowdst = qb + ((size_t)b * M_ + r0) * D_ + d0;
        trdst  = qT + ((size_t)b * D_ + d0) * M_ + r0;
        dotdst = qdot + b * M_ + r0;
        wmv = (float4){1.f, 1.f, 1.f, 1.f};
        wdv = *(const float4*)(w + d0 + c);            // w_q
        ldt = M_;
    }
#pragma unroll
    for (int i = 0; i < 4; ++i) {
        int r = i * 16 + rband;
        float4 x = *(const float4*)(src + (size_t)r * D_ + c);
        t[r][c] = x.x; t[r][c + 1] = x.y; t[r][c + 2] = x.z; t[r][c + 3] = x.w;
        __hip_bfloat16 o[4] __attribute__((aligned(8)));
        o[0] = __float2bfloat16(x.x * wmv.x);
        o[1] = __float2bfloat16(x.y * wmv.y);
        o[2] = __float2bfloat16(x.z * wmv.z);
        o[3] = __float2bfloat16(x.w * wmv.w);
        *(ushort4*)(rowdst + (size_t)r * D_ + c) = *(ushort4*)o;
        float p = x.x * wdv.x + x.y * wdv.y + x.z * wdv.z + x.w * wdv.w;
#pragma unroll
        for (int off = 1; off < 16; off <<= 1) p += __shfl_xor(p, off, 64);
        if (lr16 == 0) atomicAdd(dotdst + r, p);
    }
    __syncthreads();
    // transposed write: thread -> out-row dr = tid>>2, segment s = tid&3 (16 cols)
    const int dr = tid >> 2, sseg = tid & 3;
    __hip_bfloat16 o[16] __attribute__((aligned(16)));
#pragma unroll
    for (int j = 0; j < 16; ++j)
        o[j] = __float2bfloat16(t[sseg * 16 + j][dr]);
    __hip_bfloat16* dp = trdst + (size_t)dr * ldt + sseg * 16;
    ((short8*)dp)[0] = ((short8*)o)[0];
    ((short8*)dp)[1] = ((short8*)o)[1];
}

// ---------------- MFMA 128x128 tile core (single-buffer) ----------------

__device__ __forceinline__ void gl2lds16(const __hip_bfloat16* g, __hip_bfloat16* l) {
    __builtin_amdgcn_global_load_lds(
        (const __attribute__((address_space(1))) unsigned int*)g,
        (__attribute__((address_space(3))) unsigned int*)l, 16, 0, 0);
}

// A: [128 rows][K] row-major bf16, B: [128 cols][K] row-major bf16.
// acc[fi][fj] += A_tile * B_tile^T over K.
template<int KTOT>
__device__ __forceinline__ void mfma128(
    const __hip_bfloat16* __restrict__ Abase, int lda,
    const __hip_bfloat16* __restrict__ Bbase, int ldb,
    __hip_bfloat16* As, __hip_bfloat16* Bs, f32x4 acc[4][4])
{
    const int tid = threadIdx.x;
    const int w = tid >> 6, lane = tid & 63;
    const int quad = lane >> 4, lr = lane & 15;
    const int wr = w >> 1, wc = w & 1;
    const int srow = w * 32 + (lane >> 2);
    const int scol = (lane & 3) * 8;
    const __hip_bfloat16* ga0 = Abase + (size_t)srow * lda + scol;
    const __hip_bfloat16* ga1 = ga0 + (size_t)16 * lda;
    const __hip_bfloat16* gb0 = Bbase + (size_t)srow * ldb + scol;
    const __hip_bfloat16* gb1 = gb0 + (size_t)16 * ldb;
    __hip_bfloat16* la0 = As + w * 1024;
    __hip_bfloat16* la1 = As + w * 1024 + 512;
    __hip_bfloat16* lb0 = Bs + w * 1024;
    __hip_bfloat16* lb1 = Bs + w * 1024 + 512;
    const int aoff = (wr * 64 + lr) * 32 + quad * 8;
    const int boff = (wc * 64 + lr) * 32 + quad * 8;

    for (int k0 = 0; k0 < KTOT; k0 += 32) {
        gl2lds16(ga0, la0); gl2lds16(ga1, la1);
        gl2lds16(gb0, lb0); gl2lds16(gb1, lb1);
        ga0 += 32; ga1 += 32; gb0 += 32; gb1 += 32;
        asm volatile("s_waitcnt vmcnt(0)" ::: "memory");
        __syncthreads();
        short8 a[4], bb[4];
        const short8* ap = (const short8*)(As + aoff);
        const short8* bp = (const short8*)(Bs + boff);
#pragma unroll
        for (int fi = 0; fi < 4; ++fi) a[fi] = ap[fi * 64];
#pragma unroll
        for (int fj = 0; fj < 4; ++fj) bb[fj] = bp[fj * 64];
#pragma unroll
        for (int fi = 0; fi < 4; ++fi)
#pragma unroll
            for (int fj = 0; fj < 4; ++fj)
                acc[fi][fj] = __builtin_amdgcn_mfma_f32_16x16x32_bf16(
                    a[fi], bb[fj], acc[fi][fj], 0, 0, 0);
        __syncthreads();
    }
}

// dual-B variant: shared A tile, two accumulators.
template<int KTOT>
__device__ __forceinline__ void mfma128x2(
    const __hip_bfloat16* __restrict__ Abase, int lda,
    const __hip_bfloat16* __restrict__ B1base,
    const __hip_bfloat16* __restrict__ B2base, int ldb,
    __hip_bfloat16* As, __hip_bfloat16* B1s, __hip_bfloat16* B2s,
    f32x4 acc1[4][4], f32x4 acc2[4][4])
{
    const int tid = threadIdx.x;
    const int w = tid >> 6, lane = tid & 63;
    const int quad = lane >> 4, lr = lane & 15;
    const int wr = w >> 1, wc = w & 1;
    const int srow = w * 32 + (lane >> 2);
    const int scol = (lane & 3) * 8;
    const __hip_bfloat16* ga0 = Abase + (size_t)srow * lda + scol;
    const __hip_bfloat16* ga1 = ga0 + (size_t)16 * lda;
    const __hip_bfloat16* gb10 = B1base + (size_t)srow * ldb + scol;
    const __hip_bfloat16* gb11 = gb10 + (size_t)16 * ldb;
    const __hip_bfloat16* gb20 = B2base + (size_t)srow * ldb + scol;
    const __hip_bfloat16* gb21 = gb20 + (size_t)16 * ldb;
    __hip_bfloat16* la0 = As + w * 1024;
    __hip_bfloat16* la1 = la0 + 512;
    __hip_bfloat16* lb10 = B1s + w * 1024;
    __hip_bfloat16* lb11 = lb10 + 512;
    __hip_bfloat16* lb20 = B2s + w * 1024;
    __hip_bfloat16* lb21 = lb20 + 512;
    const int aoff = (wr * 64 + lr) * 32 + quad * 8;
    const int boff = (wc * 64 + lr) * 32 + quad * 8;

    for (int k0 = 0; k0 < KTOT; k0 += 32) {
        gl2lds16(ga0, la0); gl2lds16(ga1, la1);
        gl2lds16(gb10, lb10); gl2lds16(gb11, lb11);
        gl2lds16(gb20, lb20); gl2lds16(gb21, lb21);
        ga0 += 32; ga1 += 32; gb10 += 32; gb11 += 32; gb20 += 32; gb21 += 32;
        asm volatile("s_waitcnt vmcnt(0)" ::: "memory");
        __syncthreads();
        short8 a[4], b1[4], b2[4];
        const short8* ap = (const short8*)(As + aoff);
        const short8* bp1 = (const short8*)(B1s + boff);
        const short8* bp2 = (const short8*)(B2s + boff);
#pragma unroll
        for (int fi = 0; fi < 4; ++fi) a[fi] = ap[fi * 64];
#pragma unroll
        for (int fj = 0; fj < 4; ++fj) { b1[fj] = bp1[fj * 64]; b2[fj] = bp2[fj * 64]; }
#pragma unroll
        for (int fi = 0; fi < 4; ++fi)
#pragma unroll
            for (int fj = 0; fj < 4; ++fj) {
                acc1[fi][fj] = __builtin_amdgcn_mfma_f32_16x16x32_bf16(
                    a[fi], b1[fj], acc1[fi][fj], 0, 0, 0);
                acc2[fi][fj] = __builtin_amdgcn_mfma_f32_16x16x32_bf16(
                    a[fi], b2[fj], acc2[fi][fj], 0, 0, 0);
            }
        __syncthreads();
    }
}

#define ACC_INIT(acc) \
    _Pragma("unroll") for (int i_ = 0; i_ < 4; ++i_) \
    _Pragma("unroll") for (int j_ = 0; j_ < 4; ++j_) acc[i_][j_] = (f32x4){0.f, 0.f, 0.f, 0.f};

#define EPI_IDX const int tid = threadIdx.x, lane = tid & 63, quad = lane >> 4, lr = lane & 15; \
    const int wr = tid >> 7, wc = (tid >> 6) & 1;

// S[n][m] = ctxw[n][:] . qry[m][:] + cdot[n] + qdot[m]
// Epilogue additionally emits softmax partials:
//   row partials (over 64-col slabs, 4 per row) -> rpmax/rpsum
//   col partials (over 64-row slabs, 16 per col) -> pmax/psum
__global__ __launch_bounds__(256) void s_gemm_stats(
    const __hip_bfloat16* __restrict__ ctxw, const __hip_bfloat16* __restrict__ qryb,
    const float* __restrict__ cdot, const float* __restrict__ qdot,
    const int* __restrict__ q_mask, const int* __restrict__ c_mask,
    float* __restrict__ S,
    float* __restrict__ rpmax, float* __restrict__ rpsum,
    float* __restrict__ pmax, float* __restrict__ psum)
{
    __shared__ __align__(16) __hip_bfloat16 As[4096], Bs[4096];
    const int b = blockIdx.z, n0 = blockIdx.y * 128, m0 = blockIdx.x * 128;
    f32x4 acc[4][4];
    ACC_INIT(acc)
    mfma128<512>(ctxw + ((size_t)b * N_ + n0) * D_, D_,
                 qryb + ((size_t)b * M_ + m0) * D_, D_, As, Bs, acc);
    EPI_IDX
    float cd[4][4]; int cmv[4][4];
#pragma unroll
    for (int fi = 0; fi < 4; ++fi)
#pragma unroll
        for (int r = 0; r < 4; ++r) {
            int n = n0 + wr * 64 + fi * 16 + quad * 4 + r;
            cd[fi][r] = cdot[b * N_ + n];
            cmv[fi][r] = c_mask[b * N_ + n];
        }
    float qd[4]; int qmv[4];
#pragma unroll
    for (int fj = 0; fj < 4; ++fj) {
        int m = m0 + wc * 64 + fj * 16 + lr;
        qd[fj] = qdot[b * M_ + m];
        qmv[fj] = q_mask[b * M_ + m];
    }
    // store S
#pragma unroll
    for (int fi = 0; fi < 4; ++fi)
#pragma unroll
        for (int r = 0; r < 4; ++r) {
            int n = n0 + wr * 64 + fi * 16 + quad * 4 + r;
            size_t rowoff = ((size_t)b * N_ + n) * M_;
#pragma unroll
            for (int fj = 0; fj < 4; ++fj) {
                int m = m0 + wc * 64 + fj * 16 + lr;
                S[rowoff + m] = acc[fi][fj][r] + cd[fi][r] + qd[fj];
            }
        }
    // ---- row partial stats ----
    const int part = blockIdx.x * 2 + wc;
#pragma unroll
    for (int fi = 0; fi < 4; ++fi)
#pragma unroll
        for (int r = 0; r < 4; ++r) {
            float xs[4], mx = -1e30f;
#pragma unroll
            for (int fj = 0; fj < 4; ++fj) {
                xs[fj] = qmv[fj] ? (acc[fi][fj][r] + cd[fi][r] + qd[fj]) : -1e9f;
                mx = fmaxf(mx, xs[fj]);
            }
#pragma unroll
            for (int off = 1; off < 16; off <<= 1)
                mx = fmaxf(mx, __shfl_xor(mx, off, 64));
            float se = 0.f;
#pragma unroll
            for (int fj = 0; fj < 4; ++fj) se += __expf(xs[fj] - mx);
#pragma unroll
            for (int off = 1; off < 16; off <<= 1)
                se += __shfl_xor(se, off, 64);
            if (lr == 0) {
                int n = n0 + wr * 64 + fi * 16 + quad * 4 + r;
                rpmax[((size_t)b * N_ + n) * 4 + part] = mx;
                rpsum[((size_t)b * N_ + n) * 4 + part] = se;
            }
        }
    // ---- col partial stats ----
    const int ch = blockIdx.y * 2 + wr;
#pragma unroll
    for (int fj = 0; fj < 4; ++fj) {
        float mx = -1e30f;
#pragma unroll
        for (int fi = 0; fi < 4; ++fi)
#pragma unroll
            for (int r = 0; r < 4; ++r) {
                float x = cmv[fi][r] ? (acc[fi][fj][r] + cd[fi][r] + qd[fj]) : -1e9f;
                mx = fmaxf(mx, x);
            }
        mx = fmaxf(mx, __shfl_xor(mx, 16, 64));
        mx = fmaxf(mx, __shfl_xor(mx, 32, 64));
        float se = 0.f;
#pragma unroll
        for (int fi = 0; fi < 4; ++fi)
#pragma unroll
            for (int r = 0; r < 4; ++r) {
                float x = cmv[fi][r] ? (acc[fi][fj][r] + cd[fi][r] + qd[fj]) : -1e9f;
                se += __expf(x - mx);
            }
        se += __shfl_xor(se, 16, 64);
        se += __shfl_xor(se, 32, 64);
        if (lane < 16) {
            int m = m0 + wc * 64 + fj * 16 + lr;
            pmax[((size_t)b * 16 + ch) * M_ + m] = mx;
            psum[((size_t)b * 16 + ch) * M_ + m] = se;
        }
    }
}

// Q2CT[d][m] = sum_n ctxT[d][n] * BmT[m][n]
__global__ __launch_bounds__(256) void q2cpart_mfma(
    const __hip_bfloat16* __restrict__ ctxT, const __hip_bfloat16* __restrict__ BmT,
    __hip_bfloat16* __restrict__ Q2CT)
{
    __shared__ __align__(16) __hip_bfloat16 As[4096], Bs[4096];
    const int b = blockIdx.z, d0 = blockIdx.y * 128, m0 = blockIdx.x * 128;
    f32x4 acc[4][4];
    ACC_INIT(acc)
    mfma128<1024>(ctxT + ((size_t)b * D_ + d0) * N_, N_,
                  BmT + ((size_t)b * M_ + m0) * N_, N_, As, Bs, acc);
    EPI_IDX
#pragma unroll
    for (int fi = 0; fi < 4; ++fi) {
#pragma unroll
        for (int r = 0; r < 4; ++r) {
            int d = d0 + wr * 64 + fi * 16 + quad * 4 + r;
#pragma unroll
            for (int fj = 0; fj < 4; ++fj) {
                int m = m0 + wc * 64 + fj * 16 + lr;
                Q2CT[((size_t)b * D_ + d) * M_ + m] = __float2bfloat16(acc[fi][fj][r]);
            }
        }
    }
}

// fused: c2q[n][d] = sum_m A[n][m] qryT[d][m]
//        q2c[n][d] = sum_m A[n][m] Q2CT[d][m]
// writes all 4 output chunks: [ctx, c2q, ctx*c2q, ctx*q2c]
__global__ __launch_bounds__(256) void out_fused_mfma(
    const __hip_bfloat16* __restrict__ Anm, const __hip_bfloat16* __restrict__ qryT,
    const __hip_bfloat16* __restrict__ Q2CT, const float* __restrict__ ctx,
    float* __restrict__ out)
{
    __shared__ __align__(16) __hip_bfloat16 As[4096], B1s[4096], B2s[4096];
    const int b = blockIdx.z, n0 = blockIdx.y * 128, d0 = blockIdx.x * 128;
    f32x4 acc1[4][4], acc2[4][4];
    ACC_INIT(acc1)
    ACC_INIT(acc2)
    mfma128x2<256>(Anm + ((size_t)b * N_ + n0) * M_, M_,
                   qryT + ((size_t)b * D_ + d0) * M_,
                   Q2CT + ((size_t)b * D_ + d0) * M_, M_,
                   As, B1s, B2s, acc1, acc2);
    EPI_IDX
#pragma unroll
    for (int fi = 0; fi < 4; ++fi) {
#pragma unroll
        for (int r = 0; r < 4; ++r) {
            int n = n0 + wr * 64 + fi * 16 + quad * 4 + r;
            size_t ibase = ((size_t)b * N_ + n) * D_;
            size_t obase = ((size_t)b * N_ + n) * (4 * D_);
#pragma unroll
            for (int fj = 0; fj < 4; ++fj) {
                int d = d0 + wc * 64 + fj * 16 + lr;
                float c = ctx[ibase + d];
                float v1 = acc1[fi][fj][r];
                float v2 = acc2[fi][fj][r];
                out[obase + d] = c;
                out[obase + D_ + d] = v1;
                out[obase + 2 * D_ + d] = c * v1;
                out[obase + 3 * D_ + d] = c * v2;
            }
        }
    }
}

// ---------------- normalize (stats-combine folded in, vectorized) ----------------
// A -> Anm (bf16, [n][m]); Bm -> BmT (bf16, [m][n] via LDS transpose)
__global__ __launch_bounds__(256) void normalize_kernel(
    const float* __restrict__ S, __hip_bfloat16* __restrict__ Anm,
    __hip_bfloat16* __restrict__ BmT,
    const int* __restrict__ q_mask, const int* __restrict__ c_mask,
    const float* __restrict__ pmax, const float* __restrict__ psum,
    const float* __restrict__ rpmax, const float* __restrict__ rpsum)
{
    __shared__ float t[64][65];
    __shared__ float cmx_s[64], cinv_s[64], rmx_s[64], rinv_s[64];
    const int b = blockIdx.z, n0 = blockIdx.y * 64, m0 = blockIdx.x * 64;
    const int tid = threadIdx.x;
    // phase 0: combine partial stats for this tile's 64 cols / 64 rows
    if (tid < 64) {
        int m = m0 + tid;
        float mx = -1e30f;
#pragma unroll
        for (int ch = 0; ch < 16; ++ch)
            mx = fmaxf(mx, pmax[((size_t)b * 16 + ch) * M_ + m]);
        float sm = 0.f;
#pragma unroll
        for (int ch = 0; ch < 16; ++ch)
            sm += psum[((size_t)b * 16 + ch) * M_ + m] *
                  __expf(pmax[((size_t)b * 16 + ch) * M_ + m] - mx);
        cmx_s[tid] = mx; cinv_s[tid] = 1.0f / sm;
    } else if (tid < 128) {
        int rl = tid - 64;
        size_t row = (size_t)b * N_ + n0 + rl;
        float mx = -1e30f;
#pragma unroll
        for (int p = 0; p < 4; ++p)
            mx = fmaxf(mx, rpmax[row * 4 + p]);
        float sm = 0.f;
#pragma unroll
        for (int p = 0; p < 4; ++p)
            sm += rpsum[row * 4 + p] * __expf(rpmax[row * 4 + p] - mx);
        rmx_s[rl] = mx; rinv_s[rl] = 1.0f / sm;
    }
    __syncthreads();
    // phase 1: main pass — float4 S loads, ushort4 Anm stores, bm into LDS
    const int lr16 = tid & 15, rband = tid >> 4;
    const int c = lr16 * 4;
    int4 qm4 = *(const int4*)(q_mask + b * M_ + m0 + c);
    float cmx0 = cmx_s[c], cmx1 = cmx_s[c + 1], cmx2 = cmx_s[c + 2], cmx3 = cmx_s[c + 3];
    float ci0 = cinv_s[c], ci1 = cinv_s[c + 1], ci2 = cinv_s[c + 2], ci3 = cinv_s[c + 3];
#pragma unroll
    for (int i = 0; i < 4; ++i) {
        int r = i * 16 + rband;
        int n = n0 + r;
        int cm = c_mask[b * N_ + n];
        float rmx = rmx_s[r], rinv = rinv_s[r];
        size_t idx = ((size_t)b * N_ + n) * M_ + m0 + c;
        float4 s4 = *(const float4*)(S + idx);
        __hip_bfloat16 av[4] __attribute__((aligned(8)));
        av[0] = __float2bfloat16(qm4.x ? __expf(s4.x - rmx) * rinv : 0.f);
        av[1] = __float2bfloat16(qm4.y ? __expf(s4.y - rmx) * rinv : 0.f);
        av[2] = __float2bfloat16(qm4.z ? __expf(s4.z - rmx) * rinv : 0.f);
        av[3] = __float2bfloat16(qm4.w ? __expf(s4.w - rmx) * rinv : 0.f);
        *(ushort4*)(Anm + idx) = *(ushort4*)av;
        t[r][c]     = cm ? __expf(s4.x - cmx0) * ci0 : 0.f;
        t[r][c + 1] = cm ? __expf(s4.y - cmx1) * ci1 : 0.f;
        t[r][c + 2] = cm ? __expf(s4.z - cmx2) * ci2 : 0.f;
        t[r][c + 3] = cm ? __expf(s4.w - cmx3) * ci3 : 0.f;
    }
    __syncthreads();
    // phase 2: transposed BmT write, short8 stores
    const int mr = tid >> 2, sseg = tid & 3;
    __hip_bfloat16 o[16] __attribute__((aligned(16)));
#pragma unroll
    for (int j = 0; j < 16; ++j)
        o[j] = __float2bfloat16(t[sseg * 16 + j][mr]);
    __hip_bfloat16* dp = BmT + ((size_t)b * M_ + m0 + mr) * N_ + n0 + sseg * 16;
    ((short8*)dp)[0] = ((short8*)o)[0];
    ((short8*)dp)[1] = ((short8*)o)[1];
}

extern "C" void kernel_launch(void* const* d_in, const int* in_sizes, int n_in,
                              void* d_out, int out_size, void* d_ws, size_t ws_size,
                              hipStream_t stream) {
    const float* ctx   = (const float*)d_in[0];
    const float* qry   = (const float*)d_in[1];
    const int*   cmask = (const int*)d_in[2];
    const int*   qmask = (const int*)d_in[3];
    const float* w     = (const float*)d_in[4];
    float* out = (float*)d_out;
    float* ws  = (float*)d_ws;

    float* S = ws + OFF_S;
    __hip_bfloat16* ctxw = (__hip_bfloat16*)(ws + OFF_CTXW);
    __hip_bfloat16* Anm  = (__hip_bfloat16*)(ws + OFF_ANM);
    __hip_bfloat16* BmT  = (__hip_bfloat16*)(ws + OFF_BMT);
    __hip_bfloat16* qb   = (__hip_bfloat16*)(ws + OFF_QB);
    __hip_bfloat16* Q2CT = (__hip_bfloat16*)(ws + OFF_QB);
    __hip_bfloat16* qT   = (__hip_bfloat16*)(ws + OFF_QT);
    __hip_bfloat16* cT   = (__hip_bfloat16*)(ws + OFF_CT);
    float* cdot = ws + OFF_CDOT;
    float* qdot = ws + OFF_QDOT;
    float* pmax = ws + OFF_PMAX;
    float* psum = ws + OFF_PSUM;
    float* rpmax = ws + OFF_RPMAX;
    float* rpsum = ws + OFF_RPSUM;

    // zero dot accumulators (cdot and qdot are contiguous)
    hipMemsetAsync(cdot, 0, (size_t)(B_ * N_ + B_ * M_) * sizeof(float), stream);

    dim3 gp(D_ / 64, (N_ + M_) / 64, B_);
    prep_all<<<gp, 256, 0, stream>>>(ctx, qry, w, ctxw, cT, cdot, qb, qT, qdot);

    dim3 gS(M_ / 128, N_ / 128, B_);
    s_gemm_stats<<<gS, 256, 0, stream>>>(ctxw, qb, cdot, qdot, qmask, cmask,
                                         S, rpmax, rpsum, pmax, psum);

    dim3 gN(M_ / 64, N_ / 64, B_);
    normalize_kernel<<<gN, 256, 0, stream>>>(S, Anm, BmT, qmask, cmask,
                                             pmax, psum, rpmax, rpsum);

    dim3 gP(M_ / 128, D_ / 128, B_);
    q2cpart_mfma<<<gP, 256, 0, stream>>>(cT, BmT, Q2CT);

    dim3 gO(D_ / 128, N_ / 128, B_);
    out_fused_mfma<<<gO, 256, 0, stream>>>(Anm, qT, Q2CT, ctx, out);
}

// Round 4
// 473.049 us; speedup vs baseline: 1.0880x; 1.0189x over previous
//
#include <hip/hip_runtime.h>
#include <hip/hip_bf16.h>

#define B_ 32
#define N_ 1024
#define M_ 256
#define D_ 512

typedef __attribute__((ext_vector_type(8))) short short8;
typedef __attribute__((ext_vector_type(4))) float f32x4;

// ---- workspace layout (float offsets) ----
#define OFF_ANUM  ((size_t)0)          // bf16 Anum=exp(S-rmax) [B][N][M] (16 MB)
#define OFF_CTXW  ((size_t)8388608)    // bf16 ctx*w_m [B][N][D]  (dead after s_gemm)
#define OFF_BMT   ((size_t)12582912)   // bf16 Bm^T [B][M][N] (overlays ctxw 2nd half)
#define OFF_QB    ((size_t)16777216)   // bf16 qry [B][M][D]; Q2CT overlays after s_gemm
#define OFF_QT    ((size_t)18874368)   // bf16 qry^T [B][D][M]
#define OFF_CT    ((size_t)20971520)   // bf16 ctx^T [B][D][N]
#define OFF_CDOT  ((size_t)29360128)
#define OFF_QDOT  ((size_t)29392896)
#define OFF_PMAX  ((size_t)29483008)   // fp32 col partials [B][16][M]
#define OFF_PSUM  ((size_t)29614080)
#define OFF_RMAX  ((size_t)29745152)   // fp32 [B][N] final row max
#define OFF_RINV  ((size_t)29876224)   // fp32 [B][N] 1/rsum

// ---------------- fused prep: cast*w_m / transpose / dot ----------------
__global__ __launch_bounds__(256) void prep_all(
    const float* __restrict__ ctx, const float* __restrict__ qry,
    const float* __restrict__ w,
    __hip_bfloat16* __restrict__ ctxw, __hip_bfloat16* __restrict__ cT,
    float* __restrict__ cdot,
    __hip_bfloat16* __restrict__ qb, __hip_bfloat16* __restrict__ qT,
    float* __restrict__ qdot)
{
    __shared__ float t[64][65];
    const int b = blockIdx.z, d0 = blockIdx.x * 64;
    const int tid = threadIdx.x;
    const float* src;
    __hip_bfloat16* rowdst;
    __hip_bfloat16* trdst;
    float* dotdst;
    int ldt;
    float4 wmv, wdv;
    const int lr16 = tid & 15, rband = tid >> 4;
    const int c = lr16 * 4;
    if (blockIdx.y < N_ / 64) {
        int r0 = blockIdx.y * 64;
        src    = ctx + ((size_t)b * N_ + r0) * D_ + d0;
        rowdst = ctxw + ((size_t)b * N_ + r0) * D_ + d0;
        trdst  = cT + ((size_t)b * D_ + d0) * N_ + r0;
        dotdst = cdot + b * N_ + r0;
        wmv = *(const float4*)(w + 2 * D_ + d0 + c);   // w_m
        wdv = *(const float4*)(w + D_ + d0 + c);       // w_c
        ldt = N_;
    } else {
        int r0 = (blockIdx.y - N_ / 64) * 64;
        src    = qry + ((size_t)b * M_ + r0) * D_ + d0;
        rowdst = qb + ((size_t)b * M_ + r0) * D_ + d0;
        trdst  = qT + ((size_t)b * D_ + d0) * M_ + r0;
        dotdst = qdot + b * M_ + r0;
        wmv = (float4){1.f, 1.f, 1.f, 1.f};
        wdv = *(const float4*)(w + d0 + c);            // w_q
        ldt = M_;
    }
#pragma unroll
    for (int i = 0; i < 4; ++i) {
        int r = i * 16 + rband;
        float4 x = *(const float4*)(src + (size_t)r * D_ + c);
        t[r][c] = x.x; t[r][c + 1] = x.y; t[r][c + 2] = x.z; t[r][c + 3] = x.w;
        __hip_bfloat16 o[4] __attribute__((aligned(8)));
        o[0] = __float2bfloat16(x.x * wmv.x);
        o[1] = __float2bfloat16(x.y * wmv.y);
        o[2] = __float2bfloat16(x.z * wmv.z);
        o[3] = __float2bfloat16(x.w * wmv.w);
        *(ushort4*)(rowdst + (size_t)r * D_ + c) = *(ushort4*)o;
        float p = x.x * wdv.x + x.y * wdv.y + x.z * wdv.z + x.w * wdv.w;
#pragma unroll
        for (int off = 1; off < 16; off <<= 1) p += __shfl_xor(p, off, 64);
        if (lr16 == 0) atomicAdd(dotdst + r, p);
    }
    __syncthreads();
    const int dr = tid >> 2, sseg = tid & 3;
    __hip_bfloat16 o[16] __attribute__((aligned(16)));
#pragma unroll
    for (int j = 0; j < 16; ++j)
        o[j] = __float2bfloat16(t[sseg * 16 + j][dr]);
    __hip_bfloat16* dp = trdst + (size_t)dr * ldt + sseg * 16;
    ((short8*)dp)[0] = ((short8*)o)[0];
    ((short8*)dp)[1] = ((short8*)o)[1];
}

// ---------------- MFMA helpers ----------------

__device__ __forceinline__ void gl2lds16(const __hip_bfloat16* g, __hip_bfloat16* l) {
    __builtin_amdgcn_global_load_lds(
        (const __attribute__((address_space(1))) unsigned int*)g,
        (__attribute__((address_space(3))) unsigned int*)l, 16, 0, 0);
}

// 128x128 tile core (single-buffer), as verified in earlier rounds.
template<int KTOT>
__device__ __forceinline__ void mfma128(
    const __hip_bfloat16* __restrict__ Abase, int lda,
    const __hip_bfloat16* __restrict__ Bbase, int ldb,
    __hip_bfloat16* As, __hip_bfloat16* Bs, f32x4 acc[4][4])
{
    const int tid = threadIdx.x;
    const int w = tid >> 6, lane = tid & 63;
    const int quad = lane >> 4, lr = lane & 15;
    const int wr = w >> 1, wc = w & 1;
    const int srow = w * 32 + (lane >> 2);
    const int scol = (lane & 3) * 8;
    const __hip_bfloat16* ga0 = Abase + (size_t)srow * lda + scol;
    const __hip_bfloat16* ga1 = ga0 + (size_t)16 * lda;
    const __hip_bfloat16* gb0 = Bbase + (size_t)srow * ldb + scol;
    const __hip_bfloat16* gb1 = gb0 + (size_t)16 * ldb;
    __hip_bfloat16* la0 = As + w * 1024;
    __hip_bfloat16* la1 = As + w * 1024 + 512;
    __hip_bfloat16* lb0 = Bs + w * 1024;
    __hip_bfloat16* lb1 = Bs + w * 1024 + 512;
    const int aoff = (wr * 64 + lr) * 32 + quad * 8;
    const int boff = (wc * 64 + lr) * 32 + quad * 8;

    for (int k0 = 0; k0 < KTOT; k0 += 32) {
        gl2lds16(ga0, la0); gl2lds16(ga1, la1);
        gl2lds16(gb0, lb0); gl2lds16(gb1, lb1);
        ga0 += 32; ga1 += 32; gb0 += 32; gb1 += 32;
        asm volatile("s_waitcnt vmcnt(0)" ::: "memory");
        __syncthreads();
        short8 a[4], bb[4];
        const short8* ap = (const short8*)(As + aoff);
        const short8* bp = (const short8*)(Bs + boff);
#pragma unroll
        for (int fi = 0; fi < 4; ++fi) a[fi] = ap[fi * 64];
#pragma unroll
        for (int fj = 0; fj < 4; ++fj) bb[fj] = bp[fj * 64];
#pragma unroll
        for (int fi = 0; fi < 4; ++fi)
#pragma unroll
            for (int fj = 0; fj < 4; ++fj)
                acc[fi][fj] = __builtin_amdgcn_mfma_f32_16x16x32_bf16(
                    a[fi], bb[fj], acc[fi][fj], 0, 0, 0);
        __syncthreads();
    }
}

// dual-B variant: shared A tile, two accumulators.
template<int KTOT>
__device__ __forceinline__ void mfma128x2(
    const __hip_bfloat16* __restrict__ Abase, int lda,
    const __hip_bfloat16* __restrict__ B1base,
    const __hip_bfloat16* __restrict__ B2base, int ldb,
    __hip_bfloat16* As, __hip_bfloat16* B1s, __hip_bfloat16* B2s,
    f32x4 acc1[4][4], f32x4 acc2[4][4])
{
    const int tid = threadIdx.x;
    const int w = tid >> 6, lane = tid & 63;
    const int quad = lane >> 4, lr = lane & 15;
    const int wr = w >> 1, wc = w & 1;
    const int srow = w * 32 + (lane >> 2);
    const int scol = (lane & 3) * 8;
    const __hip_bfloat16* ga0 = Abase + (size_t)srow * lda + scol;
    const __hip_bfloat16* ga1 = ga0 + (size_t)16 * lda;
    const __hip_bfloat16* gb10 = B1base + (size_t)srow * ldb + scol;
    const __hip_bfloat16* gb11 = gb10 + (size_t)16 * ldb;
    const __hip_bfloat16* gb20 = B2base + (size_t)srow * ldb + scol;
    const __hip_bfloat16* gb21 = gb20 + (size_t)16 * ldb;
    __hip_bfloat16* la0 = As + w * 1024;
    __hip_bfloat16* la1 = la0 + 512;
    __hip_bfloat16* lb10 = B1s + w * 1024;
    __hip_bfloat16* lb11 = lb10 + 512;
    __hip_bfloat16* lb20 = B2s + w * 1024;
    __hip_bfloat16* lb21 = lb20 + 512;
    const int aoff = (wr * 64 + lr) * 32 + quad * 8;
    const int boff = (wc * 64 + lr) * 32 + quad * 8;

    for (int k0 = 0; k0 < KTOT; k0 += 32) {
        gl2lds16(ga0, la0); gl2lds16(ga1, la1);
        gl2lds16(gb10, lb10); gl2lds16(gb11, lb11);
        gl2lds16(gb20, lb20); gl2lds16(gb21, lb21);
        ga0 += 32; ga1 += 32; gb10 += 32; gb11 += 32; gb20 += 32; gb21 += 32;
        asm volatile("s_waitcnt vmcnt(0)" ::: "memory");
        __syncthreads();
        short8 a[4], b1[4], b2[4];
        const short8* ap = (const short8*)(As + aoff);
        const short8* bp1 = (const short8*)(B1s + boff);
        const short8* bp2 = (const short8*)(B2s + boff);
#pragma unroll
        for (int fi = 0; fi < 4; ++fi) a[fi] = ap[fi * 64];
#pragma unroll
        for (int fj = 0; fj < 4; ++fj) { b1[fj] = bp1[fj * 64]; b2[fj] = bp2[fj * 64]; }
#pragma unroll
        for (int fi = 0; fi < 4; ++fi)
#pragma unroll
            for (int fj = 0; fj < 4; ++fj) {
                acc1[fi][fj] = __builtin_amdgcn_mfma_f32_16x16x32_bf16(
                    a[fi], b1[fj], acc1[fi][fj], 0, 0, 0);
                acc2[fi][fj] = __builtin_amdgcn_mfma_f32_16x16x32_bf16(
                    a[fi], b2[fj], acc2[fi][fj], 0, 0, 0);
            }
        __syncthreads();
    }
}

#define ACC_INIT(acc) \
    _Pragma("unroll") for (int i_ = 0; i_ < 4; ++i_) \
    _Pragma("unroll") for (int j_ = 0; j_ < 4; ++j_) acc[i_][j_] = (f32x4){0.f, 0.f, 0.f, 0.f};

// ---------------- S-GEMM, full-M tile (128n x 256m), 512 threads ----------------
// Emits Anum = q_mask * exp(S - rmax(n)) bf16, final row stats (rmax, 1/rsum),
// and col partial stats over 64-row slabs (16 chunks, layout [B][16][M]).
// No fp32 S plane is ever materialized.
__global__ __launch_bounds__(512) void s_gemm_full(
    const __hip_bfloat16* __restrict__ ctxw, const __hip_bfloat16* __restrict__ qryb,
    const float* __restrict__ cdot, const float* __restrict__ qdot,
    const int* __restrict__ q_mask, const int* __restrict__ c_mask,
    __hip_bfloat16* __restrict__ Anum,
    float* __restrict__ rmax_g, float* __restrict__ rinv_g,
    float* __restrict__ pmax, float* __restrict__ psum)
{
    __shared__ __align__(16) __hip_bfloat16 As[4096];   // 128 x 32
    __shared__ __align__(16) __hip_bfloat16 Bs[8192];   // 256 x 32
    __shared__ float rpm[128][4], rps[128][4];
    __shared__ float rmx_s[128];
    const int b = blockIdx.y, n0 = blockIdx.x * 128;
    const int tid = threadIdx.x;
    const int w = tid >> 6, lane = tid & 63;
    const int quad = lane >> 4, lr = lane & 15;
    const int wr = w >> 2, wc = w & 3;          // 2 x 4 wave grid, wave tile 64n x 64m
    const int srow = tid >> 2, scol = (tid & 3) * 8;
    const __hip_bfloat16* gA  = ctxw + ((size_t)b * N_ + n0 + srow) * D_ + scol;
    const __hip_bfloat16* gB0 = qryb + ((size_t)b * M_ + srow) * D_ + scol;
    const __hip_bfloat16* gB1 = qryb + ((size_t)b * M_ + 128 + srow) * D_ + scol;
    __hip_bfloat16* la  = As + w * 512;
    __hip_bfloat16* lb0 = Bs + w * 512;
    __hip_bfloat16* lb1 = Bs + 4096 + w * 512;
    const int aoff = (wr * 64 + lr) * 32 + quad * 8;
    const int boff = (wc * 64 + lr) * 32 + quad * 8;

    f32x4 acc[4][4];
    ACC_INIT(acc)
    for (int k0 = 0; k0 < D_; k0 += 32) {
        gl2lds16(gA, la); gl2lds16(gB0, lb0); gl2lds16(gB1, lb1);
        gA += 32; gB0 += 32; gB1 += 32;
        asm volatile("s_waitcnt vmcnt(0)" ::: "memory");
        __syncthreads();
        short8 a[4], bb[4];
        const short8* ap = (const short8*)(As + aoff);
        const short8* bp = (const short8*)(Bs + boff);
#pragma unroll
        for (int fi = 0; fi < 4; ++fi) a[fi] = ap[fi * 64];
#pragma unroll
        for (int fj = 0; fj < 4; ++fj) bb[fj] = bp[fj * 64];
#pragma unroll
        for (int fi = 0; fi < 4; ++fi)
#pragma unroll
            for (int fj = 0; fj < 4; ++fj)
                acc[fi][fj] = __builtin_amdgcn_mfma_f32_16x16x32_bf16(
                    a[fi], bb[fj], acc[fi][fj], 0, 0, 0);
        __syncthreads();
    }

    // ---- epilogue ----
    float cd[4][4]; int cmv[4][4];
#pragma unroll
    for (int fi = 0; fi < 4; ++fi)
#pragma unroll
        for (int r = 0; r < 4; ++r) {
            int n = n0 + wr * 64 + fi * 16 + quad * 4 + r;
            cd[fi][r] = cdot[b * N_ + n];
            cmv[fi][r] = c_mask[b * N_ + n];
        }
    float qd[4]; int qmv[4];
#pragma unroll
    for (int fj = 0; fj < 4; ++fj) {
        int m = wc * 64 + fj * 16 + lr;
        qd[fj] = qdot[b * M_ + m];
        qmv[fj] = q_mask[b * M_ + m];
    }
    // row partial stats: each wave reduces its 64 cols (16 lanes x 4 fj)
#pragma unroll
    for (int fi = 0; fi < 4; ++fi)
#pragma unroll
        for (int r = 0; r < 4; ++r) {
            float xs[4], mx = -1e30f;
#pragma unroll
            for (int fj = 0; fj < 4; ++fj) {
                xs[fj] = qmv[fj] ? (acc[fi][fj][r] + cd[fi][r] + qd[fj]) : -1e9f;
                mx = fmaxf(mx, xs[fj]);
            }
#pragma unroll
            for (int off = 1; off < 16; off <<= 1)
                mx = fmaxf(mx, __shfl_xor(mx, off, 64));
            float se = 0.f;
#pragma unroll
            for (int fj = 0; fj < 4; ++fj) se += __expf(xs[fj] - mx);
#pragma unroll
            for (int off = 1; off < 16; off <<= 1)
                se += __shfl_xor(se, off, 64);
            if (lr == 0) {
                int nl = wr * 64 + fi * 16 + quad * 4 + r;
                rpm[nl][wc] = mx; rps[nl][wc] = se;
            }
        }
    __syncthreads();
    // combine 4 wave partials per row -> final row stats
    if (tid < 128) {
        float m0v = rpm[tid][0], m1 = rpm[tid][1], m2 = rpm[tid][2], m3 = rpm[tid][3];
        float mx = fmaxf(fmaxf(m0v, m1), fmaxf(m2, m3));
        float sm = rps[tid][0] * __expf(m0v - mx) + rps[tid][1] * __expf(m1 - mx)
                 + rps[tid][2] * __expf(m2 - mx) + rps[tid][3] * __expf(m3 - mx);
        float inv = 1.0f / sm;
        rmx_s[tid] = mx;
        rmax_g[b * N_ + n0 + tid] = mx;
        rinv_g[b * N_ + n0 + tid] = inv;
    }
    __syncthreads();
    // Anum = q_mask * exp(S - rmax) -> bf16
#pragma unroll
    for (int fi = 0; fi < 4; ++fi)
#pragma unroll
        for (int r = 0; r < 4; ++r) {
            int nl = wr * 64 + fi * 16 + quad * 4 + r;
            float rmx = rmx_s[nl];
            size_t rowoff = ((size_t)b * N_ + n0 + nl) * M_;
#pragma unroll
            for (int fj = 0; fj < 4; ++fj) {
                int m = wc * 64 + fj * 16 + lr;
                float sv = acc[fi][fj][r] + cd[fi][r] + qd[fj];
                float a = qmv[fj] ? __expf(sv - rmx) : 0.f;
                Anum[rowoff + m] = __float2bfloat16(a);
            }
        }
    // col partial stats over this block's two 64-row slabs
    const int ch = blockIdx.x * 2 + wr;
#pragma unroll
    for (int fj = 0; fj < 4; ++fj) {
        float mx = -1e30f;
#pragma unroll
        for (int fi = 0; fi < 4; ++fi)
#pragma unroll
            for (int r = 0; r < 4; ++r) {
                float x = cmv[fi][r] ? (acc[fi][fj][r] + cd[fi][r] + qd[fj]) : -1e9f;
                mx = fmaxf(mx, x);
            }
        mx = fmaxf(mx, __shfl_xor(mx, 16, 64));
        mx = fmaxf(mx, __shfl_xor(mx, 32, 64));
        float se = 0.f;
#pragma unroll
        for (int fi = 0; fi < 4; ++fi)
#pragma unroll
            for (int r = 0; r < 4; ++r) {
                float x = cmv[fi][r] ? (acc[fi][fj][r] + cd[fi][r] + qd[fj]) : -1e9f;
                se += __expf(x - mx);
            }
        se += __shfl_xor(se, 16, 64);
        se += __shfl_xor(se, 32, 64);
        if (lane < 16) {
            int m = wc * 64 + fj * 16 + lr;
            pmax[((size_t)b * 16 + ch) * M_ + m] = mx;
            psum[((size_t)b * 16 + ch) * M_ + m] = se;
        }
    }
}

// ---------------- normalize: Anum -> BmT (rank-1 correction) ----------------
// Bm[n][m] = c_mask[n] * Anum[n][m] * exp(rmax(n) - cmax(m)) / csum(m)
__global__ __launch_bounds__(256) void normalize_bm(
    const __hip_bfloat16* __restrict__ Anum, __hip_bfloat16* __restrict__ BmT,
    const int* __restrict__ c_mask,
    const float* __restrict__ pmax, const float* __restrict__ psum,
    const float* __restrict__ rmax_g)
{
    __shared__ float t[64][65];
    __shared__ float cmx_s[64], cinv_s[64], rmx_s[64];
    const int b = blockIdx.z, n0 = blockIdx.y * 64, m0 = blockIdx.x * 64;
    const int tid = threadIdx.x;
    if (tid < 64) {
        int m = m0 + tid;
        float mx = -1e30f;
#pragma unroll
        for (int ch = 0; ch < 16; ++ch)
            mx = fmaxf(mx, pmax[((size_t)b * 16 + ch) * M_ + m]);
        float sm = 0.f;
#pragma unroll
        for (int ch = 0; ch < 16; ++ch)
            sm += psum[((size_t)b * 16 + ch) * M_ + m] *
                  __expf(pmax[((size_t)b * 16 + ch) * M_ + m] - mx);
        cmx_s[tid] = mx; cinv_s[tid] = 1.0f / sm;
    } else if (tid < 128) {
        int rl = tid - 64;
        rmx_s[rl] = rmax_g[(size_t)b * N_ + n0 + rl];
    }
    __syncthreads();
    const int lr8 = tid & 7, rband = tid >> 3;     // 8 cols x 32 rows
    const int c = lr8 * 8;
#pragma unroll
    for (int i = 0; i < 2; ++i) {
        int r = i * 32 + rband;
        int n = n0 + r;
        int cm = c_mask[b * N_ + n];
        float rmx = rmx_s[r];
        short8 a8 = *(const short8*)(Anum + ((size_t)b * N_ + n) * M_ + m0 + c);
#pragma unroll
        for (int j = 0; j < 8; ++j) {
            int ml = c + j;
            float anv = __bfloat162float(*(const __hip_bfloat16*)&((short*)&a8)[j]);
            t[r][ml] = cm ? anv * __expf(rmx - cmx_s[ml]) * cinv_s[ml] : 0.f;
        }
    }
    __syncthreads();
    const int mr = tid >> 2, sseg = tid & 3;
    __hip_bfloat16 o[16] __attribute__((aligned(16)));
#pragma unroll
    for (int j = 0; j < 16; ++j)
        o[j] = __float2bfloat16(t[sseg * 16 + j][mr]);
    __hip_bfloat16* dp = BmT + ((size_t)b * M_ + m0 + mr) * N_ + n0 + sseg * 16;
    ((short8*)dp)[0] = ((short8*)o)[0];
    ((short8*)dp)[1] = ((short8*)o)[1];
}

#define EPI_IDX const int tid = threadIdx.x, lane = tid & 63, quad = lane >> 4, lr = lane & 15; \
    const int wr = tid >> 7, wc = (tid >> 6) & 1;

// Q2CT[d][m] = sum_n ctxT[d][n] * BmT[m][n]
__global__ __launch_bounds__(256) void q2cpart_mfma(
    const __hip_bfloat16* __restrict__ ctxT, const __hip_bfloat16* __restrict__ BmT,
    __hip_bfloat16* __restrict__ Q2CT)
{
    __shared__ __align__(16) __hip_bfloat16 As[4096], Bs[4096];
    const int b = blockIdx.z, d0 = blockIdx.y * 128, m0 = blockIdx.x * 128;
    f32x4 acc[4][4];
    ACC_INIT(acc)
    mfma128<1024>(ctxT + ((size_t)b * D_ + d0) * N_, N_,
                  BmT + ((size_t)b * M_ + m0) * N_, N_, As, Bs, acc);
    EPI_IDX
#pragma unroll
    for (int fi = 0; fi < 4; ++fi) {
#pragma unroll
        for (int r = 0; r < 4; ++r) {
            int d = d0 + wr * 64 + fi * 16 + quad * 4 + r;
#pragma unroll
            for (int fj = 0; fj < 4; ++fj) {
                int m = m0 + wc * 64 + fj * 16 + lr;
                Q2CT[((size_t)b * D_ + d) * M_ + m] = __float2bfloat16(acc[fi][fj][r]);
            }
        }
    }
}

// fused: c2q[n][d] = rinv(n) * sum_m Anum[n][m] qryT[d][m]
//        q2c[n][d] = rinv(n) * sum_m Anum[n][m] Q2CT[d][m]
// writes all 4 output chunks: [ctx, c2q, ctx*c2q, ctx*q2c]
__global__ __launch_bounds__(256) void out_fused_mfma(
    const __hip_bfloat16* __restrict__ Anum, const __hip_bfloat16* __restrict__ qryT,
    const __hip_bfloat16* __restrict__ Q2CT, const float* __restrict__ ctx,
    const float* __restrict__ rinv_g, float* __restrict__ out)
{
    __shared__ __align__(16) __hip_bfloat16 As[4096], B1s[4096], B2s[4096];
    const int b = blockIdx.z, n0 = blockIdx.y * 128, d0 = blockIdx.x * 128;
    f32x4 acc1[4][4], acc2[4][4];
    ACC_INIT(acc1)
    ACC_INIT(acc2)
    mfma128x2<256>(Anum + ((size_t)b * N_ + n0) * M_, M_,
                   qryT + ((size_t)b * D_ + d0) * M_,
                   Q2CT + ((size_t)b * D_ + d0) * M_, M_,
                   As, B1s, B2s, acc1, acc2);
    EPI_IDX
#pragma unroll
    for (int fi = 0; fi < 4; ++fi) {
#pragma unroll
        for (int r = 0; r < 4; ++r) {
            int n = n0 + wr * 64 + fi * 16 + quad * 4 + r;
            float rinv = rinv_g[(size_t)b * N_ + n];
            size_t ibase = ((size_t)b * N_ + n) * D_;
            size_t obase = ((size_t)b * N_ + n) * (4 * D_);
#pragma unroll
            for (int fj = 0; fj < 4; ++fj) {
                int d = d0 + wc * 64 + fj * 16 + lr;
                float c = ctx[ibase + d];
                float v1 = acc1[fi][fj][r] * rinv;
                float v2 = acc2[fi][fj][r] * rinv;
                out[obase + d] = c;
                out[obase + D_ + d] = v1;
                out[obase + 2 * D_ + d] = c * v1;
                out[obase + 3 * D_ + d] = c * v2;
            }
        }
    }
}

extern "C" void kernel_launch(void* const* d_in, const int* in_sizes, int n_in,
                              void* d_out, int out_size, void* d_ws, size_t ws_size,
                              hipStream_t stream) {
    const float* ctx   = (const float*)d_in[0];
    const float* qry   = (const float*)d_in[1];
    const int*   cmask = (const int*)d_in[2];
    const int*   qmask = (const int*)d_in[3];
    const float* w     = (const float*)d_in[4];
    float* out = (float*)d_out;
    float* ws  = (float*)d_ws;

    __hip_bfloat16* Anum = (__hip_bfloat16*)(ws + OFF_ANUM);
    __hip_bfloat16* ctxw = (__hip_bfloat16*)(ws + OFF_CTXW);
    __hip_bfloat16* BmT  = (__hip_bfloat16*)(ws + OFF_BMT);
    __hip_bfloat16* qb   = (__hip_bfloat16*)(ws + OFF_QB);
    __hip_bfloat16* Q2CT = (__hip_bfloat16*)(ws + OFF_QB);
    __hip_bfloat16* qT   = (__hip_bfloat16*)(ws + OFF_QT);
    __hip_bfloat16* cT   = (__hip_bfloat16*)(ws + OFF_CT);
    float* cdot = ws + OFF_CDOT;
    float* qdot = ws + OFF_QDOT;
    float* pmax = ws + OFF_PMAX;
    float* psum = ws + OFF_PSUM;
    float* rmax = ws + OFF_RMAX;
    float* rinv = ws + OFF_RINV;

    hipMemsetAsync(cdot, 0, (size_t)(B_ * N_ + B_ * M_) * sizeof(float), stream);

    dim3 gp(D_ / 64, (N_ + M_) / 64, B_);
    prep_all<<<gp, 256, 0, stream>>>(ctx, qry, w, ctxw, cT, cdot, qb, qT, qdot);

    dim3 gS(N_ / 128, B_);
    s_gemm_full<<<gS, 512, 0, stream>>>(ctxw, qb, cdot, qdot, qmask, cmask,
                                        Anum, rmax, rinv, pmax, psum);

    dim3 gN(M_ / 64, N_ / 64, B_);
    normalize_bm<<<gN, 256, 0, stream>>>(Anum, BmT, cmask, pmax, psum, rmax);

    dim3 gP(M_ / 128, D_ / 128, B_);
    q2cpart_mfma<<<gP, 256, 0, stream>>>(cT, BmT, Q2CT);

    dim3 gO(D_ / 128, N_ / 128, B_);
    out_fused_mfma<<<gO, 256, 0, stream>>>(Anum, qT, Q2CT, ctx, rinv, out);
}